// Round 4
// baseline (672.199 us; speedup 1.0000x reference)
//
#include <hip/hip_runtime.h>

typedef __bf16 bf16;
typedef __bf16 bf16x4 __attribute__((ext_vector_type(4)));
typedef __bf16 bf16x8 __attribute__((ext_vector_type(8)));
typedef float  f32x4  __attribute__((ext_vector_type(4)));

// async global->LDS, 16B per lane; LDS dest is wave-uniform base + lane*16
__device__ inline void async_copy16(void* lds, const void* g) {
  __builtin_amdgcn_global_load_lds((const __attribute__((address_space(1))) void*)g,
                                   (__attribute__((address_space(3))) void*)lds,
                                   16, 0, 0);
}

// 4x4 transpose among the 4 lanes {l, l+16, l+32, l+48}; cg = lane>>4.
// In: v[j] = M[j][cg].  Out: v[i] = M[cg][i].   (verified element-wise)
__device__ inline void xpose4(float v[4], int cg) {
  float a = (cg & 2) ? v[0] : v[2];
  float b = (cg & 2) ? v[1] : v[3];
  float ra = __shfl_xor(a, 32, 64);
  float rb = __shfl_xor(b, 32, 64);
  if (cg & 2) { v[0] = ra; v[1] = rb; } else { v[2] = ra; v[3] = rb; }
  float c = (cg & 1) ? v[0] : v[1];
  float d = (cg & 1) ? v[2] : v[3];
  float rc = __shfl_xor(c, 16, 64);
  float rd = __shfl_xor(d, 16, 64);
  if (cg & 1) { v[0] = rc; v[2] = rd; } else { v[1] = rc; v[3] = rd; }
}

// ---------------- fp32 -> bf16 convert (weights) ----------------
__global__ __launch_bounds__(256)
void f2bf_kernel(const float* __restrict__ in, bf16* __restrict__ out, int n4) {
  int i = blockIdx.x * 256 + threadIdx.x;
  if (i < n4) {
    float4 v = ((const float4*)in)[i];
    bf16x4 o;
    o[0] = (bf16)v.x; o[1] = (bf16)v.y; o[2] = (bf16)v.z; o[3] = (bf16)v.w;
    ((bf16x4*)out)[i] = o;
  }
}

// ---------------- GEMM1 (transpose-fused): hb[m,1024] = x[b,:,hw] . w1b^T ----------------
// A is read straight from x fp32 [B,C,HW] (hw-contiguous); the c-transpose happens
// in-register (xpose4) during staging, then ds_write_b64 into the swizzled [m][k]
// LDS layout. B (w1b) staged via global_load_lds as before. XCD-aware block map.
// Fused BN-stats partial sums in the epilogue.
__global__ __launch_bounds__(256, 3)
void gemm1(const float* __restrict__ X, const bf16* __restrict__ Bt,
           bf16* __restrict__ Cb, float* __restrict__ S1, float* __restrict__ S2) {
  __shared__ __align__(16) bf16 As[128 * 64];
  __shared__ __align__(16) bf16 Bs[128 * 64];
  const int K = 2048, N = 1024;
  const int tid  = threadIdx.x;
  const int wave = tid >> 6;
  const int lane = tid & 63;
  const int id = blockIdx.x;                 // 2048 blocks
  const int bm = (id & 7) * 32 + ((id >> 3) >> 3);
  const int bn = (id >> 3) & 7;
  const int wr = wave >> 1, wc = wave & 1;
  const int srow = lane >> 3;
  const int scol = (lane & 7) ^ srow;        // B staging swizzled chunk

  // A staging lane decomposition
  const int cg  = lane >> 4;                 // 0..3: which c within a quad
  const int hw4 = lane & 15;                 // 16 hw-quads
  const int cgq = wave >> 1;                 // c-quad low bit
  const int mh  = wave & 1;                  // m half (0/1)
  const int ml  = mh * 64 + hw4 * 4 + cg;    // m row this lane writes after xpose
  const int mlsw = 2 * (ml & 7);             // write-side sub XOR

  f32x4 acc[4][4];
#pragma unroll
  for (int r = 0; r < 4; ++r)
#pragma unroll
    for (int c = 0; c < 4; ++c) acc[r][c] = (f32x4){0.f, 0.f, 0.f, 0.f};

  const int b   = bm >> 3;
  const int hw0 = (bm & 7) * 128;
  const float* Xg = X + (size_t)b * 2048 * 1024 + hw0 + mh * 64 + hw4 * 4;
  const bf16* Bg = Bt + (size_t)(bn * 128) * K;

  const int mrow = lane & 15;
  const int kq = lane >> 4;
  const int sw = mrow & 7;
  const bf16* Asw = As + (wr * 64) * 64;
  const bf16* Bsw = Bs + (wc * 64) * 64;

  for (int k0 = 0; k0 < K; k0 += 64) {
    // B: async global->LDS (128 rows, 4 per-wave groups)
#pragma unroll
    for (int j = 0; j < 4; ++j) {
      const int row = j * 32 + wave * 8;
      async_copy16((void*)(Bs + row * 64),
                   (const void*)(Bg + (size_t)(row + srow) * K + k0 + scol * 8));
    }
    // A: fp32 load + lane-transpose + bf16 ds_write, 2 rounds of 4 quad-sets
#pragma unroll
    for (int h = 0; h < 2; ++h) {
      float4 xa[4];
#pragma unroll
      for (int s = 0; s < 4; ++s) {
        const int cq = (h * 4 + s) * 2 + cgq;           // c-quad 0..15
        xa[s] = *(const float4*)(Xg + (size_t)(k0 + cq * 4 + cg) * 1024);
      }
#pragma unroll
      for (int s = 0; s < 4; ++s) {
        const int cq = (h * 4 + s) * 2 + cgq;
        float v[4] = {xa[s].x, xa[s].y, xa[s].z, xa[s].w};
        xpose4(v, cg);
        bf16x4 o;
        o[0] = (bf16)v[0]; o[1] = (bf16)v[1]; o[2] = (bf16)v[2]; o[3] = (bf16)v[3];
        *(bf16x4*)(As + ml * 64 + (cq ^ mlsw) * 4) = o;  // sub = 4 bf16 = 8 B
      }
    }
    __syncthreads();
#pragma unroll
    for (int kk = 0; kk < 2; ++kk) {
      bf16x8 af[4], bfr[4];
      const int lc = kk * 4 + kq;
#pragma unroll
      for (int r = 0; r < 4; ++r)
        af[r] = *(const bf16x8*)(Asw + (r * 16 + mrow) * 64 + ((lc ^ sw) * 8));
#pragma unroll
      for (int c = 0; c < 4; ++c)
        bfr[c] = *(const bf16x8*)(Bsw + (c * 16 + mrow) * 64 + ((lc ^ sw) * 8));
#pragma unroll
      for (int r = 0; r < 4; ++r)
#pragma unroll
        for (int c = 0; c < 4; ++c)
          acc[r][c] = __builtin_amdgcn_mfma_f32_16x16x32_bf16(af[r], bfr[c], acc[r][c], 0, 0, 0);
    }
    __syncthreads();
  }

  // C/D layout: col = lane&15, row = (lane>>4)*4 + reg
  const int crow = (lane >> 4) * 4;
  const int ccol = lane & 15;
#pragma unroll
  for (int r = 0; r < 4; ++r)
#pragma unroll
    for (int c = 0; c < 4; ++c)
#pragma unroll
      for (int i = 0; i < 4; ++i) {
        const int gm = bm * 128 + wr * 64 + r * 16 + crow + i;
        const int gn = bn * 128 + wc * 64 + c * 16 + ccol;
        Cb[(size_t)gm * N + gn] = (bf16)acc[r][c][i];
      }

  // Fused BN-stats partials: per-column sum/sumsq over this block's 128 rows.
  float s1[4], s2[4];
#pragma unroll
  for (int c = 0; c < 4; ++c) {
    float a = 0.f, bb = 0.f;
#pragma unroll
    for (int r = 0; r < 4; ++r)
#pragma unroll
      for (int i = 0; i < 4; ++i) { const float v = acc[r][c][i]; a += v; bb += v * v; }
#pragma unroll
    for (int msk = 16; msk < 64; msk <<= 1) { a += __shfl_xor(a, msk, 64); bb += __shfl_xor(bb, msk, 64); }
    s1[c] = a; s2[c] = bb;
  }
  float* S1s = (float*)As;        // [2][128]
  float* S2s = S1s + 256;         // [2][128]
  if ((lane & 15) == lane) {      // lanes 0..15 of each wave
#pragma unroll
    for (int c = 0; c < 4; ++c) {
      S1s[wr * 128 + wc * 64 + c * 16 + lane] = s1[c];
      S2s[wr * 128 + wc * 64 + c * 16 + lane] = s2[c];
    }
  }
  __syncthreads();
  if (tid < 128) {
    atomicAdd(&S1[bn * 128 + tid], S1s[tid] + S1s[128 + tid]);
    atomicAdd(&S2[bn * 128 + tid], S2s[tid] + S2s[128 + tid]);
  }
}

// ---------------- BN finalize: S1/S2 -> scale/shift ----------------
__global__ __launch_bounds__(256)
void bn_finalize(const float* __restrict__ S1, const float* __restrict__ S2,
                 const float* __restrict__ gamma, const float* __restrict__ beta,
                 float* __restrict__ scale, float* __restrict__ shift) {
  const int d = blockIdx.x * 256 + threadIdx.x;  // 1024 channels
  const float inv_n = 1.0f / 32768.0f;
  const float mean = S1[d] * inv_n;
  const float var  = S2[d] * inv_n - mean * mean;
  const float rstd = rsqrtf(var + 1e-5f);
  const float sc = gamma[d] * rstd;
  scale[d] = sc;
  shift[d] = beta[d] - mean * sc;
}

// ---------------- GEMM2 fused: f = relu(hb*scale+shift) . w2b^T, row-L2-norm, g-accum --------
// 512 threads (8 waves, 2x4), tile 128m x 256n, BK=64. scale/shift preloaded to LDS
// (broadcast-address ds_reads in the K-loop; no global vmcnt stall per kk).
__global__ __launch_bounds__(512, 4)
void gemm2f(const bf16* __restrict__ A, const bf16* __restrict__ Bt,
            const float* __restrict__ scale, const float* __restrict__ shift,
            float* __restrict__ g) {
  __shared__ __align__(16) bf16 As[128 * 64];
  __shared__ __align__(16) bf16 Bs[256 * 64];
  __shared__ __align__(16) float scs[1024];
  __shared__ __align__(16) float shs[1024];
  const int K = 1024;
  const int tid  = threadIdx.x;
  const int wave = tid >> 6;
  const int lane = tid & 63;
  const int bm = blockIdx.x;                 // 256 blocks, full 256-wide rows
  const int wr = wave >> 2, wc = wave & 3;   // 2 x 4 wave grid, wave tile 64x64
  const int srow = lane >> 3;
  const int scol = (lane & 7) ^ srow;

  if (tid < 256) {
    ((float4*)scs)[tid] = ((const float4*)scale)[tid];
    ((float4*)shs)[tid] = ((const float4*)shift)[tid];
  }

  f32x4 acc[4][4];
#pragma unroll
  for (int r = 0; r < 4; ++r)
#pragma unroll
    for (int c = 0; c < 4; ++c) acc[r][c] = (f32x4){0.f, 0.f, 0.f, 0.f};

  const bf16* Ag = A + (size_t)(bm * 128) * K;

  const int mrow = lane & 15;
  const int kq = lane >> 4;
  const int sw = mrow & 7;
  const bf16* Asw = As + (wr * 64) * 64;
  const bf16* Bsw = Bs + (wc * 64) * 64;
  __syncthreads();   // scs/shs visible

  for (int k0 = 0; k0 < K; k0 += 64) {
#pragma unroll
    for (int j = 0; j < 2; ++j) {
      const int row = wave * 16 + j * 8;
      async_copy16((void*)(As + row * 64),
                   (const void*)(Ag + (size_t)(row + srow) * K + k0 + scol * 8));
    }
#pragma unroll
    for (int j = 0; j < 4; ++j) {
      const int row = wave * 32 + j * 8;
      async_copy16((void*)(Bs + row * 64),
                   (const void*)(Bt + (size_t)(row + srow) * K + k0 + scol * 8));
    }
    __syncthreads();
#pragma unroll
    for (int kk = 0; kk < 2; ++kk) {
      const int lc = kk * 4 + kq;           // logical k-chunk
      const int kbase = k0 + lc * 8;
      const float4 sc0 = *(const float4*)(scs + kbase);
      const float4 sc1 = *(const float4*)(scs + kbase + 4);
      const float4 sh0 = *(const float4*)(shs + kbase);
      const float4 sh1 = *(const float4*)(shs + kbase + 4);
      const float scv[8] = {sc0.x, sc0.y, sc0.z, sc0.w, sc1.x, sc1.y, sc1.z, sc1.w};
      const float shv[8] = {sh0.x, sh0.y, sh0.z, sh0.w, sh1.x, sh1.y, sh1.z, sh1.w};
      bf16x8 af[4], bfr[4];
#pragma unroll
      for (int r = 0; r < 4; ++r) {
        bf16x8 a = *(const bf16x8*)(Asw + (r * 16 + mrow) * 64 + ((lc ^ sw) * 8));
#pragma unroll
        for (int j = 0; j < 8; ++j)
          a[j] = (bf16)fmaxf(0.f, fmaf((float)a[j], scv[j], shv[j]));
        af[r] = a;
      }
#pragma unroll
      for (int c = 0; c < 4; ++c)
        bfr[c] = *(const bf16x8*)(Bsw + (c * 16 + mrow) * 64 + ((lc ^ sw) * 8));
#pragma unroll
      for (int r = 0; r < 4; ++r)
#pragma unroll
        for (int c = 0; c < 4; ++c)
          acc[r][c] = __builtin_amdgcn_mfma_f32_16x16x32_bf16(af[r], bfr[c], acc[r][c], 0, 0, 0);
    }
    __syncthreads();
  }

  // ---- epilogue: row L2 norms + g accumulation (f never hits HBM) ----
  float* ss4   = (float*)As;      // [4 wc][128 rows]
  float* inv_s = ss4 + 512;       // [128]
  const int q = lane >> 4;
#pragma unroll
  for (int r = 0; r < 4; ++r) {
    float ssv[4];
#pragma unroll
    for (int i = 0; i < 4; ++i) {
      float s = 0.f;
#pragma unroll
      for (int c = 0; c < 4; ++c) { const float v = acc[r][c][i]; s += v * v; }
#pragma unroll
      for (int msk = 1; msk < 16; msk <<= 1) s += __shfl_xor(s, msk, 64);
      ssv[i] = s;
    }
    if ((lane & 15) == 0)
#pragma unroll
      for (int i = 0; i < 4; ++i)
        ss4[wc * 128 + wr * 64 + r * 16 + q * 4 + i] = ssv[i];
  }
  __syncthreads();
  if (tid < 128) {
    const float rs = ss4[tid] + ss4[128 + tid] + ss4[256 + tid] + ss4[384 + tid];
    inv_s[tid] = 1.0f / fmaxf(sqrtf(rs), 1e-12f);
  }
  __syncthreads();
  const int b = bm >> 3;
  const int ccol = lane & 15;
#pragma unroll
  for (int c = 0; c < 4; ++c) {
    float gl = 0.f;
#pragma unroll
    for (int r = 0; r < 4; ++r)
#pragma unroll
      for (int i = 0; i < 4; ++i)
        gl += acc[r][c][i] * inv_s[wr * 64 + r * 16 + q * 4 + i];
#pragma unroll
    for (int msk = 16; msk < 64; msk <<= 1) gl += __shfl_xor(gl, msk, 64);
    if ((lane & 48) == 0)
      atomicAdd(&g[b * 256 + wc * 64 + c * 16 + ccol], gl);
  }
}

// ---------------- normalize prototypes + sim = g . p_norm^T ----------------
__global__ __launch_bounds__(256)
void sim_kernel(const float* __restrict__ g, const float* __restrict__ protos,
                float* __restrict__ out) {
  const int wave = threadIdx.x >> 6, lane = threadIdx.x & 63;
  const int n = blockIdx.x * 4 + wave;  // 1000 prototypes, grid 250
  const float4 p = *(const float4*)(protos + (size_t)n * 256 + lane * 4);
  float ss = p.x * p.x + p.y * p.y + p.z * p.z + p.w * p.w;
#pragma unroll
  for (int msk = 1; msk < 64; msk <<= 1) ss += __shfl_xor(ss, msk, 64);
  const float inv = 1.0f / fmaxf(sqrtf(ss), 1e-12f);
  const float px = p.x * inv, py = p.y * inv, pz = p.z * inv, pw = p.w * inv;
  for (int b = 0; b < 32; ++b) {
    const float4 gv = *(const float4*)(g + b * 256 + lane * 4);
    float d = px * gv.x + py * gv.y + pz * gv.z + pw * gv.w;
#pragma unroll
    for (int msk = 1; msk < 64; msk <<= 1) d += __shfl_xor(d, msk, 64);
    if (lane == 0) out[b * 1000 + n] = d;
  }
}

extern "C" void kernel_launch(void* const* d_in, const int* in_sizes, int n_in,
                              void* d_out, int out_size, void* d_ws, size_t ws_size,
                              hipStream_t stream) {
  const float* x      = (const float*)d_in[0];  // [32,2048,32,32]
  const float* w1     = (const float*)d_in[1];  // [1024,2048]
  const float* gamma  = (const float*)d_in[2];  // [1024]
  const float* beta   = (const float*)d_in[3];  // [1024]
  const float* w2     = (const float*)d_in[4];  // [256,1024]
  const float* protos = (const float*)d_in[5];  // [1000,256]
  float* out = (float*)d_out;                   // [32,1000]

  char* ws = (char*)d_ws;
  // layout (bytes):
  //   0        : hb  [32768,1024] bf16 (64 MiB)
  //   64 MiB   : w1b [1024,2048]  bf16 ( 4 MiB)
  //   68 MiB   : w2b [256,1024]   bf16 (0.5 MiB)
  //   then     : S1(4K) S2(4K) g(32K) scale(4K) shift(4K)
  bf16*  hb    = (bf16*)(ws);
  bf16*  w1b   = (bf16*)(ws + (size_t)67108864);
  bf16*  w2b   = (bf16*)(ws + (size_t)71303168);
  float* S1    = (float*)(ws + (size_t)71827456);
  float* S2    = (float*)(ws + (size_t)71831552);
  float* g     = (float*)(ws + (size_t)71835648);
  float* scale = (float*)(ws + (size_t)71868416);
  float* shift = (float*)(ws + (size_t)71872512);

  hipMemsetAsync(S1, 0, 40960, stream);  // S1 + S2 + g contiguous

  f2bf_kernel<<<2048, 256, 0, stream>>>(w1, w1b, 524288);
  f2bf_kernel<<<256, 256, 0, stream>>>(w2, w2b, 65536);
  gemm1<<<2048, 256, 0, stream>>>(x, w1b, hb, S1, S2);
  bn_finalize<<<4, 256, 0, stream>>>(S1, S2, gamma, beta, scale, shift);
  gemm2f<<<256, 512, 0, stream>>>(hb, w2b, scale, shift, g);
  sim_kernel<<<250, 256, 0, stream>>>(g, protos, out);
}